// Round 4
// baseline (4358.383 us; speedup 1.0000x reference)
//
#include <hip/hip_runtime.h>
#include <hip/hip_bf16.h>

#define NN 1024
#define HD 64
#define TJ 128
#define EPSV 1e-5f
#define BIGINF 1e5f

__device__ __forceinline__ float siluf(float v) { return v / (1.0f + __expf(-v)); }
__device__ __forceinline__ float pnorm(float dx, float dy, float dz) {
    return sqrtf(dx * dx + dy * dy + dz * dz + EPSV);
}
__device__ __forceinline__ float wsum(float v) {
#pragma unroll
    for (int off = 32; off > 0; off >>= 1) v += __shfl_xor(v, off, 64);
    return v;
}

// ---- kA: HA = h@ew1[0:64], HB = h@ew1[64:128] + eb1 ----
__global__ void kA(const float* __restrict__ h, const float* __restrict__ ew1,
                   const float* __restrict__ eb1, float* __restrict__ HA,
                   float* __restrict__ HB) {
    const int i = blockIdx.x, o = threadIdx.x;
    float hv = h[i * HD + o];
    float a = 0.f, b = eb1[o];
#pragma unroll
    for (int k = 0; k < HD; k++) {
        float hk = __shfl(hv, k, 64);
        a += hk * ew1[k * HD + o];
        b += hk * ew1[(HD + k) * HD + o];
    }
    HA[i * HD + o] = a;
    HB[i * HD + o] = b;
}

// ---- kB: pass 1 — h_e, semantic logits ls, phi -> xupd ----
__global__ __launch_bounds__(256, 2) void kB(
    const float* __restrict__ x, const float* __restrict__ ew1,
    const float* __restrict__ ew2, const float* __restrict__ eb2,
    const float* __restrict__ cw1, const float* __restrict__ cb1,
    const float* __restrict__ cw2, const float* __restrict__ aw,
    const float* __restrict__ ab, const float* __restrict__ HA,
    const float* __restrict__ HB, float* __restrict__ ls,
    float* __restrict__ xupd) {
    const int o = threadIdx.x & 63;
    const int i = blockIdx.x * 4 + (threadIdx.x >> 6);  // wave -> i (uniform)
    const int j0 = blockIdx.y * TJ;

    float wce[64], wcc[64];  // ew2 / cw1 column o, register-resident
#pragma unroll
    for (int k = 0; k < 64; k++) wce[k] = ew2[k * 64 + o];
#pragma unroll
    for (int k = 0; k < 64; k++) wcc[k] = cw1[k * 64 + o];
    const float w1l = ew1[128 * 64 + o];
    const float eb2o = eb2[o];
    const float cb1o = cb1[o];
    const float awo = aw[o];
    const float cw2o = cw2[o];
    const float ab0 = ab[0];
    const float HAio = HA[i * 64 + o];
    const float xi0 = x[i * 3 + 0], xi1 = x[i * 3 + 1], xi2 = x[i * 3 + 2];

    float xacc = 0.f;
    for (int j = j0; j < j0 + TJ; ++j) {
        float dx = xi0 - x[j * 3 + 0];
        float dy = xi1 - x[j * 3 + 1];
        float dz = xi2 - x[j * 3 + 2];
        float nrm = pnorm(dx, dy, dz);
        float pre = HAio + HB[j * 64 + o] + nrm * w1l;
        float u = siluf(pre);
        float a0 = 0.f, a1 = 0.f, a2 = 0.f, a3 = 0.f;
#pragma unroll
        for (int k = 0; k < 64; k += 4) {
            a0 += __shfl(u, k + 0, 64) * wce[k + 0];
            a1 += __shfl(u, k + 1, 64) * wce[k + 1];
            a2 += __shfl(u, k + 2, 64) * wce[k + 2];
            a3 += __shfl(u, k + 3, 64) * wce[k + 3];
        }
        float he = eb2o + ((a0 + a1) + (a2 + a3));
        float sv = wsum(he * awo) + ab0;
        sv = sv >= 0.f ? sv : 0.01f * sv;
        if (i == j) sv -= BIGINF;
        if (o == 0) ls[(size_t)i * NN + j] = sv;
        float b0 = 0.f, b1 = 0.f, b2 = 0.f, b3 = 0.f;
#pragma unroll
        for (int k = 0; k < 64; k += 4) {
            b0 += __shfl(he, k + 0, 64) * wcc[k + 0];
            b1 += __shfl(he, k + 1, 64) * wcc[k + 1];
            b2 += __shfl(he, k + 2, 64) * wcc[k + 2];
            b3 += __shfl(he, k + 3, 64) * wcc[k + 3];
        }
        float p = cb1o + ((b0 + b1) + (b2 + b3));
        float ph = wsum(siluf(p) * cw2o);
        float dxi = (o == 0) ? dx : ((o == 1) ? dy : dz);
        if (o < 3) xacc += dxi * ph;
    }
    if (o < 3) atomicAdd(&xupd[i * 3 + o], xacc);
}

// ---- kC: per-row softmax stats -> rowm = m_e+m_s, rowd = S + EPS*Ze*Zs ----
__global__ void kC(const float* __restrict__ x, const float* __restrict__ lg,
                   const float* __restrict__ ls, float* __restrict__ rowm,
                   float* __restrict__ rowd) {
    const int i = blockIdx.x;
    const int t = threadIdx.x;  // 256 threads
    const float gamma = __expf(lg[0]);
    const float xi0 = x[i * 3 + 0], xi1 = x[i * 3 + 1], xi2 = x[i * 3 + 2];
    float le[4], lv[4];
    float me = -3.0e38f, ms = -3.0e38f;
#pragma unroll
    for (int q = 0; q < 4; q++) {
        int j = t + q * 256;
        float dx = xi0 - x[j * 3 + 0];
        float dy = xi1 - x[j * 3 + 1];
        float dz = xi2 - x[j * 3 + 2];
        float nrm = pnorm(dx, dy, dz);
        float l = -(nrm + (i == j ? BIGINF : 0.f)) * gamma;
        le[q] = l;
        lv[q] = ls[(size_t)i * NN + j];
        me = fmaxf(me, l);
        ms = fmaxf(ms, lv[q]);
    }
    __shared__ float sm[4], ss[4], s1[4], s2[4], s3[4];
#pragma unroll
    for (int off = 32; off > 0; off >>= 1) {
        me = fmaxf(me, __shfl_xor(me, off, 64));
        ms = fmaxf(ms, __shfl_xor(ms, off, 64));
    }
    const int w = t >> 6;
    if ((t & 63) == 0) { sm[w] = me; ss[w] = ms; }
    __syncthreads();
    me = fmaxf(fmaxf(sm[0], sm[1]), fmaxf(sm[2], sm[3]));
    ms = fmaxf(fmaxf(ss[0], ss[1]), fmaxf(ss[2], ss[3]));
    float Se = 0.f, Ss = 0.f, Sq = 0.f;
#pragma unroll
    for (int q = 0; q < 4; q++) {
        float ee = __expf(le[q] - me);
        float es = __expf(lv[q] - ms);
        Se += ee; Ss += es; Sq += ee * es;
    }
    Se = wsum(Se); Ss = wsum(Ss); Sq = wsum(Sq);
    if ((t & 63) == 0) { s1[w] = Se; s2[w] = Ss; s3[w] = Sq; }
    __syncthreads();
    if (t == 0) {
        float Te = s1[0] + s1[1] + s1[2] + s1[3];
        float Ts = s2[0] + s2[1] + s2[2] + s2[3];
        float Tq = s3[0] + s3[1] + s3[2] + s3[3];
        rowm[i] = me + ms;
        rowd[i] = Tq + EPSV * Te * Ts;
    }
}

// ---- kD: pass 2 — comb, h_agg, coeff -> combos ----
__global__ __launch_bounds__(256, 2) void kD(
    const float* __restrict__ x, const float* __restrict__ ew1,
    const float* __restrict__ ew2, const float* __restrict__ eb2,
    const float* __restrict__ fw1, const float* __restrict__ fb1,
    const float* __restrict__ fw2, const float* __restrict__ fb2,
    const float* __restrict__ lg, const float* __restrict__ HA,
    const float* __restrict__ HB, const float* __restrict__ ls,
    const float* __restrict__ rowm, const float* __restrict__ rowd,
    float* __restrict__ hagg, float* __restrict__ combos) {
    const int o = threadIdx.x & 63;
    const int i = blockIdx.x * 4 + (threadIdx.x >> 6);
    const int j0 = blockIdx.y * TJ;
    const int c = o & 31;

    float wce[64], wcf[64], wf2[64];
#pragma unroll
    for (int k = 0; k < 64; k++) wce[k] = ew2[k * 64 + o];
#pragma unroll
    for (int k = 0; k < 64; k++) wcf[k] = fw1[k * 64 + o];
#pragma unroll
    for (int k = 0; k < 64; k++) wf2[k] = fw2[k * 32 + c];
    const float w1l = ew1[128 * 64 + o];
    const float eb2o = eb2[o];
    const float fb1o = fb1[o];
    const float fb2c = fb2[c];
    const float gamma = __expf(lg[0]);
    const float HAio = HA[i * 64 + o];
    const float rm = rowm[i];
    const float invd = 1.0f / rowd[i];
    const float xi0 = x[i * 3 + 0], xi1 = x[i * 3 + 1], xi2 = x[i * 3 + 2];

    float hacc = 0.f, ca0 = 0.f, ca1 = 0.f, ca2 = 0.f;
    for (int j = j0; j < j0 + TJ; ++j) {
        float dx = xi0 - x[j * 3 + 0];
        float dy = xi1 - x[j * 3 + 1];
        float dz = xi2 - x[j * 3 + 2];
        float nrm = pnorm(dx, dy, dz);
        float pre = HAio + HB[j * 64 + o] + nrm * w1l;
        float u = siluf(pre);
        float a0 = 0.f, a1 = 0.f, a2 = 0.f, a3 = 0.f;
#pragma unroll
        for (int k = 0; k < 64; k += 4) {
            a0 += __shfl(u, k + 0, 64) * wce[k + 0];
            a1 += __shfl(u, k + 1, 64) * wce[k + 1];
            a2 += __shfl(u, k + 2, 64) * wce[k + 2];
            a3 += __shfl(u, k + 3, 64) * wce[k + 3];
        }
        float he = eb2o + ((a0 + a1) + (a2 + a3));
        float lsv = ls[(size_t)i * NN + j];
        float le = -(nrm + (i == j ? BIGINF : 0.f)) * gamma;
        float comb = __expf(le + lsv - rm) * invd;
        hacc += he * comb;
        float b0 = 0.f, b1 = 0.f, b2 = 0.f, b3 = 0.f;
#pragma unroll
        for (int k = 0; k < 64; k += 4) {
            b0 += __shfl(he, k + 0, 64) * wcf[k + 0];
            b1 += __shfl(he, k + 1, 64) * wcf[k + 1];
            b2 += __shfl(he, k + 2, 64) * wcf[k + 2];
            b3 += __shfl(he, k + 3, 64) * wcf[k + 3];
        }
        float V = (b0 + b1) + (b2 + b3);
        float wv = siluf(comb * V + fb1o);
        float c0 = 0.f, c1 = 0.f, c2 = 0.f, c3 = 0.f;
#pragma unroll
        for (int k = 0; k < 64; k += 4) {
            c0 += __shfl(wv, k + 0, 64) * wf2[k + 0];
            c1 += __shfl(wv, k + 1, 64) * wf2[k + 1];
            c2 += __shfl(wv, k + 2, 64) * wf2[k + 2];
            c3 += __shfl(wv, k + 3, 64) * wf2[k + 3];
        }
        float cf = fb2c + ((c0 + c1) + (c2 + c3));
        float inv1 = 1.0f / (nrm + 1.0f);
        ca0 += cf * dx * inv1;
        ca1 += cf * dy * inv1;
        ca2 += cf * dz * inv1;
    }
    atomicAdd(&hagg[i * 64 + o], hacc);
    if (o < 32) {
        atomicAdd(&combos[i * 96 + c * 3 + 0], ca0);
        atomicAdd(&combos[i * 96 + c * 3 + 1], ca1);
        atomicAdd(&combos[i * 96 + c * 3 + 2], ca2);
    }
}

// ---- kE: post MLPs + node update + coordinate output (fp32 out) ----
__global__ void kE(const float* __restrict__ h, const float* __restrict__ x,
                   const float* __restrict__ nw1, const float* __restrict__ nb1,
                   const float* __restrict__ nw2, const float* __restrict__ nb2,
                   const float* __restrict__ pw1, const float* __restrict__ pb1,
                   const float* __restrict__ pw2, const float* __restrict__ pb2,
                   const float* __restrict__ hagg, const float* __restrict__ combos,
                   const float* __restrict__ xupd, float* __restrict__ out) {
    const int i = blockIdx.x, o = threadIdx.x;
    const float invN = 1.0f / (float)NN;
    float r = 0.f;
    if (o < 32) {
        float v0 = combos[i * 96 + o * 3 + 0] * invN;
        float v1 = combos[i * 96 + o * 3 + 1] * invN;
        float v2 = combos[i * 96 + o * 3 + 2] * invN;
        r = v0 * v0 + v1 * v1 + v2 * v2;
    }
    float t1 = pb1[o];
#pragma unroll
    for (int k = 0; k < 32; k++) t1 += __shfl(r, k, 64) * pw1[k * 64 + o];
    t1 = siluf(t1);
    float hc = pb2[o];
#pragma unroll
    for (int k = 0; k < 64; k++) hc += __shfl(t1, k, 64) * pw2[k * 64 + o];
    float hi = h[i * 64 + o];
    float ha = hagg[i * 64 + o];
    float t2 = nb1[o];
#pragma unroll
    for (int k = 0; k < 64; k++) t2 += __shfl(hi, k, 64) * nw1[k * 64 + o];
#pragma unroll
    for (int k = 0; k < 64; k++) t2 += __shfl(ha, k, 64) * nw1[(64 + k) * 64 + o];
#pragma unroll
    for (int k = 0; k < 64; k++) t2 += __shfl(hc, k, 64) * nw1[(128 + k) * 64 + o];
    t2 = siluf(t2);
    float ho = hi + nb2[o];
#pragma unroll
    for (int k = 0; k < 64; k++) ho += __shfl(t2, k, 64) * nw2[k * 64 + o];
    out[i * 64 + o] = ho;
    if (o < 3)
        out[NN * 64 + i * 3 + o] = x[i * 3 + o] + xupd[i * 3 + o] * invN;
}

extern "C" void kernel_launch(void* const* d_in, const int* in_sizes, int n_in,
                              void* d_out, int out_size, void* d_ws, size_t ws_size,
                              hipStream_t stream) {
    (void)in_sizes; (void)n_in; (void)out_size; (void)ws_size;
    const float* h   = (const float*)d_in[0];
    const float* x   = (const float*)d_in[1];
    const float* ew1 = (const float*)d_in[2];
    const float* eb1 = (const float*)d_in[3];
    const float* ew2 = (const float*)d_in[4];
    const float* eb2 = (const float*)d_in[5];
    const float* nw1 = (const float*)d_in[6];
    const float* nb1 = (const float*)d_in[7];
    const float* nw2 = (const float*)d_in[8];
    const float* nb2 = (const float*)d_in[9];
    const float* cw1 = (const float*)d_in[10];
    const float* cb1 = (const float*)d_in[11];
    const float* cw2 = (const float*)d_in[12];
    const float* aw  = (const float*)d_in[13];
    const float* ab  = (const float*)d_in[14];
    const float* fw1 = (const float*)d_in[15];
    const float* fb1 = (const float*)d_in[16];
    const float* fw2 = (const float*)d_in[17];
    const float* fb2 = (const float*)d_in[18];
    const float* pw1 = (const float*)d_in[19];
    const float* pb1 = (const float*)d_in[20];
    const float* pw2 = (const float*)d_in[21];
    const float* pb2 = (const float*)d_in[22];
    const float* lg  = (const float*)d_in[23];
    float* out = (float*)d_out;

    float* W      = (float*)d_ws;
    float* ls     = W;                       // N*N
    float* HA     = ls + (size_t)NN * NN;    // N*64
    float* HB     = HA + NN * 64;            // N*64
    float* rowm   = HB + NN * 64;            // N
    float* rowd   = rowm + NN;               // N
    float* hagg   = rowd + NN;               // N*64   (atomic acc)
    float* combos = hagg + NN * 64;          // N*96   (atomic acc)
    float* xupd   = combos + NN * 96;        // N*3    (atomic acc)

    hipMemsetAsync(hagg, 0, (size_t)(NN * 64 + NN * 96 + NN * 3) * sizeof(float), stream);
    kA<<<NN, 64, 0, stream>>>(h, ew1, eb1, HA, HB);
    dim3 gB(NN / 4, NN / TJ);
    kB<<<gB, 256, 0, stream>>>(x, ew1, ew2, eb2, cw1, cb1, cw2, aw, ab, HA, HB, ls, xupd);
    kC<<<NN, 256, 0, stream>>>(x, lg, ls, rowm, rowd);
    kD<<<gB, 256, 0, stream>>>(x, ew1, ew2, eb2, fw1, fb1, fw2, fb2, lg, HA, HB, ls,
                               rowm, rowd, hagg, combos);
    kE<<<NN, 64, 0, stream>>>(h, x, nw1, nb1, nw2, nb2, pw1, pb1, pw2, pb2,
                              hagg, combos, xupd, out);
}